// Round 17
// baseline (345.332 us; speedup 1.0000x reference)
//
#include <hip/hip_runtime.h>
#include <hip/hip_fp16.h>
#include <math.h>

#define HH 128
#define WW 128
#define NPIX 16384
#define CIN 3
#define DD 32
#define QQ 128
#define MM 16
#define NBATCH 2
#define EPSF 1e-8f

typedef _Float16 half4_t __attribute__((ext_vector_type(4)));
typedef float f32x4_t __attribute__((ext_vector_type(4)));

// ---------------- conv1: 3x3, 3->32, relu, zero-pad SAME ----------------
__global__ __launch_bounds__(256) void conv1_kernel(
    const float* __restrict__ x, const float* __restrict__ w1,
    const float* __restrict__ b1, float* __restrict__ out)
{
    __shared__ float wlds[9 * CIN * DD];
    int t = threadIdx.x;
    for (int idx = t; idx < 9 * CIN * DD / 4; idx += 256)
        ((float4*)wlds)[idx] = ((const float4*)w1)[idx];
    __syncthreads();

    int ocq = t & 3;
    int pl  = t >> 2;
    int blk = blockIdx.x;                   // 512
    int b   = blk >> 8;
    int pix = (blk & 255) * 64 + pl;
    int i = pix >> 7, j = pix & 127;
    int ocb = ocq << 3;

    float4 acc0 = *(const float4*)(b1 + ocb);
    float4 acc1 = *(const float4*)(b1 + ocb + 4);
    #pragma unroll
    for (int dy = 0; dy < 3; dy++) {
        int ii = i + dy - 1;
        if (ii < 0 || ii >= HH) continue;
        #pragma unroll
        for (int dx = 0; dx < 3; dx++) {
            int jj = j + dx - 1;
            if (jj < 0 || jj >= WW) continue;
            const float* fr = x + ((size_t)((b << 14) + ii * WW + jj)) * CIN;
            float in0 = fr[0], in1 = fr[1], in2 = fr[2];
            const float* wp = wlds + (size_t)((dy * 3 + dx) * CIN) * DD + ocb;
            #pragma unroll
            for (int ic = 0; ic < 3; ic++) {
                float inv = (ic == 0) ? in0 : (ic == 1) ? in1 : in2;
                float4 w0 = *(const float4*)(wp + ic * DD);
                float4 w1v = *(const float4*)(wp + ic * DD + 4);
                acc0.x += inv * w0.x;  acc0.y += inv * w0.y;
                acc0.z += inv * w0.z;  acc0.w += inv * w0.w;
                acc1.x += inv * w1v.x; acc1.y += inv * w1v.y;
                acc1.z += inv * w1v.z; acc1.w += inv * w1v.w;
            }
        }
    }
    float* op = out + (((size_t)(b << 14) + pix) << 5) + ocb;
    float4 r0 = {fmaxf(acc0.x, 0.f), fmaxf(acc0.y, 0.f), fmaxf(acc0.z, 0.f), fmaxf(acc0.w, 0.f)};
    float4 r1 = {fmaxf(acc1.x, 0.f), fmaxf(acc1.y, 0.f), fmaxf(acc1.z, 0.f), fmaxf(acc1.w, 0.f)};
    *(float4*)op = r0;
    *(float4*)(op + 4) = r1;
}

// ---------------- conv2: 3x3, 32->32, relu (proven R7 version) -----------
__global__ __launch_bounds__(256) void conv2_kernel(
    const float* __restrict__ fin, const float* __restrict__ w2,
    const float* __restrict__ b2, float* __restrict__ out)
{
    __shared__ float wlds[9 * DD * DD];    // 36.9 KB
    int t = threadIdx.x;
    for (int idx = t; idx < 9 * DD * DD / 4; idx += 256)
        ((float4*)wlds)[idx] = ((const float4*)w2)[idx];
    __syncthreads();

    int ocq = t & 3;
    int pl  = t >> 2;
    int blk = blockIdx.x;                   // 512
    int b   = blk >> 8;
    int pix = (blk & 255) * 64 + pl;
    int i = pix >> 7, j = pix & 127;
    int ocb = ocq << 3;

    float4 acc0 = *(const float4*)(b2 + ocb);
    float4 acc1 = *(const float4*)(b2 + ocb + 4);
    #pragma unroll
    for (int dy = 0; dy < 3; dy++) {
        int ii = i + dy - 1;
        if (ii < 0 || ii >= HH) continue;
        #pragma unroll
        for (int dx = 0; dx < 3; dx++) {
            int jj = j + dx - 1;
            if (jj < 0 || jj >= WW) continue;
            const float* fr = fin + (((size_t)(b << 14) + ii * WW + jj)) * DD;
            float iv[DD];
            #pragma unroll
            for (int c = 0; c < DD / 4; c++)
                ((float4*)iv)[c] = *(const float4*)(fr + c * 4);
            const float* wp = wlds + (size_t)((dy * 3 + dx) * DD) * DD + ocb;
            #pragma unroll
            for (int ic = 0; ic < DD; ic++) {
                float inv = iv[ic];
                float4 w0 = *(const float4*)(wp + ic * DD);
                float4 w1v = *(const float4*)(wp + ic * DD + 4);
                acc0.x += inv * w0.x;  acc0.y += inv * w0.y;
                acc0.z += inv * w0.z;  acc0.w += inv * w0.w;
                acc1.x += inv * w1v.x; acc1.y += inv * w1v.y;
                acc1.z += inv * w1v.z; acc1.w += inv * w1v.w;
            }
        }
    }
    float* op = out + (((size_t)(b << 14) + pix) << 5) + ocb;
    float4 r0 = {fmaxf(acc0.x, 0.f), fmaxf(acc0.y, 0.f), fmaxf(acc0.z, 0.f), fmaxf(acc0.w, 0.f)};
    float4 r1 = {fmaxf(acc1.x, 0.f), fmaxf(acc1.y, 0.f), fmaxf(acc1.z, 0.f), fmaxf(acc1.w, 0.f)};
    *(float4*)op = r0;
    *(float4*)(op + 4) = r1;
}

// ---------------- k/q 1x1 projections + row norms ----------------
__global__ __launch_bounds__(256) void kq_kernel(
    const float* __restrict__ fin, const float* __restrict__ wk,
    const float* __restrict__ bk, const float* __restrict__ wq,
    float* __restrict__ ksb, float* __restrict__ qsb,
    float* __restrict__ knorm, float* __restrict__ qnorm)
{
    int g  = blockIdx.x * 256 + threadIdx.x;  // B*N*32
    int oc = g & 31;
    int bp = g >> 5;
    const float* fr = fin + (size_t)bp * DD;
    float ak = bk[oc], aq = 0.0f;
    #pragma unroll
    for (int ic = 0; ic < DD; ic += 4) {
        float4 fv = *(const float4*)(fr + ic);
        ak += fv.x * wk[(ic + 0) * DD + oc];
        ak += fv.y * wk[(ic + 1) * DD + oc];
        ak += fv.z * wk[(ic + 2) * DD + oc];
        ak += fv.w * wk[(ic + 3) * DD + oc];
        aq += fv.x * wq[(ic + 0) * DD + oc];
        aq += fv.y * wq[(ic + 1) * DD + oc];
        aq += fv.z * wq[(ic + 2) * DD + oc];
        aq += fv.w * wq[(ic + 3) * DD + oc];
    }
    ksb[g] = ak;
    qsb[g] = aq;
    float ssk = ak * ak, ssq = aq * aq;
    #pragma unroll
    for (int m = 1; m < 32; m <<= 1) {
        ssk += __shfl_xor(ssk, m, 64);
        ssq += __shfl_xor(ssq, m, 64);
    }
    if (oc == 0) {
        knorm[bp] = sqrtf(ssk);
        qnorm[bp] = sqrtf(ssq);
    }
}

// ---------------- edge scores: exp(cosine), UNSCALED ---------------------
__global__ __launch_bounds__(256) void edge_kernel(
    const float* __restrict__ ksb, const float* __restrict__ qsb,
    const float* __restrict__ knorm, const float* __restrict__ qnorm,
    float* __restrict__ wT)
{
    __shared__ float kt[144][36];   // +4 pad: breaks 32-stride bank aliasing
    __shared__ float qt[64][36];
    __shared__ float kn[144];
    __shared__ float qn[64];
    const int t   = threadIdx.x;
    const int blk = blockIdx.x;     // 512
    const int b   = blk >> 8;
    const int tl  = blk & 255;
    const int ti0 = (tl >> 4) << 3, tj0 = (tl & 15) << 3;
    const float* kb = ksb + ((size_t)b << 19);
    const float* qb = qsb + ((size_t)b << 19);

    for (int idx = t; idx < 144 * 8; idx += 256) {
        int row = idx >> 3, quad = idx & 7;
        int ar = row / 12, ac = row - ar * 12;
        int gi = min(max(ti0 + ar - 2, 0), HH - 1);
        int gj = min(max(tj0 + ac - 2, 0), WW - 1);
        *(float4*)&kt[row][quad << 2] =
            *(const float4*)(kb + ((size_t)(gi * WW + gj) << 5) + (quad << 2));
    }
    for (int idx = t; idx < 64 * 8; idx += 256) {
        int row = idx >> 3, quad = idx & 7;
        int gp = (ti0 + (row >> 3)) * WW + tj0 + (row & 7);
        *(float4*)&qt[row][quad << 2] =
            *(const float4*)(qb + ((size_t)gp << 5) + (quad << 2));
    }
    if (t < 144) {
        int ar = t / 12, ac = t - ar * 12;
        int gi = min(max(ti0 + ar - 2, 0), HH - 1);
        int gj = min(max(tj0 + ac - 2, 0), WW - 1);
        kn[t] = knorm[(b << 14) + gi * WW + gj];
    } else if (t < 208) {
        int r2 = t - 144;
        int gp = (ti0 + (r2 >> 3)) * WW + tj0 + (r2 & 7);
        qn[r2] = qnorm[(b << 14) + gp];
    }
    __syncthreads();

    const int nl = t >> 2, s = t & 3;
    const int p = nl >> 3, q = nl & 7;
    float4 qv[8];
    #pragma unroll
    for (int c = 0; c < 8; c++) qv[c] = *(const float4*)&qt[nl][c << 2];
    const float qnv = qn[nl];
    const int gp = (ti0 + p) * WW + tj0 + q;
    float* wrow = wT + (((size_t)(b << 14) + gp) << 5);
    for (int o = s; o < 25; o += 4) {
        int di = o / 5, dj = o - di * 5;      // 0..4
        int krow = (p + di) * 12 + (q + dj);  // halo coords
        const float* kr = &kt[krow][0];
        float dot = 0.0f;
        #pragma unroll
        for (int c = 0; c < 8; c++) {
            float4 kv = *(const float4*)(kr + (c << 2));
            dot += qv[c].x * kv.x + qv[c].y * kv.y + qv[c].z * kv.z + qv[c].w * kv.w;
        }
        float den = fmaxf(qnv * kn[krow], EPSF);
        wrow[o] = expf(dot / den);
    }
}

// ---------------- W pack: dense zero-padded fp16 W[64 own][144 halo] -----
__global__ __launch_bounds__(256) void wpack_kernel(
    const float* __restrict__ wT, __half* __restrict__ Wg)
{
    __shared__ __half Wl[64 * 144];        // 18,432 B
    const int t = threadIdx.x;
    const int x = blockIdx.x & 7;
    const int r = blockIdx.x >> 3;
    const int g_tr = (x << 2) + (r >> 4);
    const int b   = g_tr >> 4;
    const int ti0 = (g_tr & 15) << 3;
    const int tj0 = (r & 15) << 3;

    for (int idx = t; idx < 1152; idx += 256)
        ((uint4*)Wl)[idx] = (uint4){0u, 0u, 0u, 0u};
    __syncthreads();

    const int own = t >> 2, k4 = t & 3;
    const int p = own >> 3, q = own & 7;
    const int gp = (ti0 + p) * WW + tj0 + q;
    const float* wrow = wT + (((size_t)(b << 14) + gp) << 5);
    for (int o = k4; o < 25; o += 4) {
        int di = o / 5, dj = o - di * 5;
        int a = (p + di) * 12 + (q + dj);   // halo K index 0..143 (all distinct)
        Wl[own * 144 + a] = __float2half(wrow[o]);
    }
    __syncthreads();

    uint4* dst = (uint4*)(Wg + (size_t)blockIdx.x * 9216);
    for (int idx = t; idx < 1152; idx += 256)
        dst[idx] = ((uint4*)Wl)[idx];
}

// ---------------- propagation iteration: MFMA 16x16x16 GEMM --------------
// OUT[64 own][128 ch] = W[64x144] x H[144 halo][128 ch] per tile.
// (R16-proven structure: crossbar tr-read, K=144 = 9 x mfma_16x16x16f16,
// A from L2-resident Wg, one barrier, rule-18 fences. 333.6 us total.)
// NEW: epilogue LDS-transpose -- the old 32 scattered 2-B global stores
// per thread (4 disjoint 32-B segments per wave instr) are replaced by
// conflict-free LDS writes into reused Hs ([own][132] rows: lgrp stride
// 264 words = 8 mod 32 banks -> 4 groups on disjoint bank octets), then
// 8 fully-coalesced uint2 global stores per thread (512 B/wave/instr).
template<bool FIRST>
__global__ __launch_bounds__(256) void prop_mfma_kernel(
    const void* __restrict__ hin_v, __half* __restrict__ hout,
    const __half* __restrict__ Wg)
{
    __shared__ __half Hs[8 * 2320];        // 37,120 B: [nt][144][16] + 16 pad
    const int t = threadIdx.x;
    const int x = blockIdx.x & 7;          // XCD slab
    const int r = blockIdx.x >> 3;
    const int g_tr = (x << 2) + (r >> 4);
    const int b   = g_tr >> 4;
    const int ti0 = (g_tr & 15) << 3;
    const int tj0 = (r & 15) << 3;

    const int s = t & 15, g = t >> 4;
    // stage H: 9 halo px/thread, 8 ch (ch = s*8..s*8+7 -> nt=s>>1, hi=s&1)
    {
        const int nt_s = s >> 1, hi = s & 1;
        uint4* hd = (uint4*)Hs;
        #pragma unroll
        for (int n = 0; n < 9; n++) {
            int a = (n << 4) + g;
            int ar = a / 12, ac = a - ar * 12;
            int gi = min(max(ti0 + ar - 2, 0), HH - 1);
            int gj = min(max(tj0 + ac - 2, 0), WW - 1);
            size_t src = (((size_t)(b << 14) + gi * WW + gj) << 7) + (s << 3);
            uint4 v;
            if constexpr (FIRST) {
                const float* hb = (const float*)hin_v;
                float4 f0 = *(const float4*)(hb + src);
                float4 f1 = *(const float4*)(hb + src + 4);
                __half2 p0 = __floats2half2_rn(f0.x, f0.y);
                __half2 p1 = __floats2half2_rn(f0.z, f0.w);
                __half2 p2 = __floats2half2_rn(f1.x, f1.y);
                __half2 p3 = __floats2half2_rn(f1.z, f1.w);
                v.x = *(unsigned*)&p0; v.y = *(unsigned*)&p1;
                v.z = *(unsigned*)&p2; v.w = *(unsigned*)&p3;
            } else {
                const __half* hb = (const __half*)hin_v;
                v = *(const uint4*)(hb + src);
            }
            hd[nt_s * 290 + (a << 1) + hi] = v;   // halves: nt*2320 + a*16 + hi*8
        }
    }

    const int mt = t >> 6, lane = t & 63;
    const int l15 = lane & 15, lgrp = lane >> 4;

    // A-fragments from L2-resident Wg: lane reads W[mt*16+l15][kk*16+lgrp*4 ..+3]
    const __half* wrow_g = Wg + (size_t)blockIdx.x * 9216
                              + ((mt << 4) + l15) * 144 + (lgrp << 2);
    half4_t Af[9];
    #pragma unroll
    for (int kk = 0; kk < 9; kk++)
        Af[kk] = *(const half4_t*)(wrow_g + (kk << 4));

    __syncthreads();

    f32x4_t acc[8];
    #pragma unroll
    for (int nt = 0; nt < 8; nt++) acc[nt] = (f32x4_t){0.f, 0.f, 0.f, 0.f};

    // crossbar addressing: lane covers its own 8 B of the group's 128-B
    // 4x16 window; window = rows lgrp*4..lgrp*4+3 of the kk K-subtile
    const unsigned hsb = (unsigned)(size_t)&Hs[0]
                       + ((unsigned)l15 << 3) + ((unsigned)lgrp << 7);
    #pragma unroll
    for (int nt = 0; nt < 8; nt++) {
        unsigned base = hsb + (unsigned)nt * 4640u;
        unsigned long long r0, r1, r2, r3, r4, r5, r6, r7, r8;
        asm volatile("ds_read_b64_tr_b16 %0, %1"              : "=v"(r0) : "v"(base));
        asm volatile("ds_read_b64_tr_b16 %0, %1 offset:512"   : "=v"(r1) : "v"(base));
        asm volatile("ds_read_b64_tr_b16 %0, %1 offset:1024"  : "=v"(r2) : "v"(base));
        asm volatile("ds_read_b64_tr_b16 %0, %1 offset:1536"  : "=v"(r3) : "v"(base));
        asm volatile("ds_read_b64_tr_b16 %0, %1 offset:2048"  : "=v"(r4) : "v"(base));
        asm volatile("ds_read_b64_tr_b16 %0, %1 offset:2560"  : "=v"(r5) : "v"(base));
        asm volatile("ds_read_b64_tr_b16 %0, %1 offset:3072"  : "=v"(r6) : "v"(base));
        asm volatile("ds_read_b64_tr_b16 %0, %1 offset:3584"  : "=v"(r7) : "v"(base));
        asm volatile("ds_read_b64_tr_b16 %0, %1 offset:4096"  : "=v"(r8) : "v"(base));
        asm volatile("s_waitcnt lgkmcnt(0)" ::: "memory");
        __builtin_amdgcn_sched_barrier(0);
        union { unsigned long long u; half4_t h; } b0, b1, b2, b3, b4, b5, b6, b7, b8;
        b0.u = r0; b1.u = r1; b2.u = r2; b3.u = r3; b4.u = r4;
        b5.u = r5; b6.u = r6; b7.u = r7; b8.u = r8;
        acc[nt] = __builtin_amdgcn_mfma_f32_16x16x16f16(Af[0], b0.h, acc[nt], 0, 0, 0);
        acc[nt] = __builtin_amdgcn_mfma_f32_16x16x16f16(Af[1], b1.h, acc[nt], 0, 0, 0);
        acc[nt] = __builtin_amdgcn_mfma_f32_16x16x16f16(Af[2], b2.h, acc[nt], 0, 0, 0);
        acc[nt] = __builtin_amdgcn_mfma_f32_16x16x16f16(Af[3], b3.h, acc[nt], 0, 0, 0);
        acc[nt] = __builtin_amdgcn_mfma_f32_16x16x16f16(Af[4], b4.h, acc[nt], 0, 0, 0);
        acc[nt] = __builtin_amdgcn_mfma_f32_16x16x16f16(Af[5], b5.h, acc[nt], 0, 0, 0);
        acc[nt] = __builtin_amdgcn_mfma_f32_16x16x16f16(Af[6], b6.h, acc[nt], 0, 0, 0);
        acc[nt] = __builtin_amdgcn_mfma_f32_16x16x16f16(Af[7], b7.h, acc[nt], 0, 0, 0);
        acc[nt] = __builtin_amdgcn_mfma_f32_16x16x16f16(Af[8], b8.h, acc[nt], 0, 0, 0);
    }

    // ---- epilogue phase 1: normalize, write into reused Hs [own][132] ----
    __syncthreads();                       // all waves' tr-reads done
    {
        #pragma unroll
        for (int j = 0; j < 4; j++) {
            float ss = 0.0f;
            #pragma unroll
            for (int nt = 0; nt < 8; nt++) { float v = acc[nt][j]; ss += v * v; }
            ss += __shfl_xor(ss, 1, 64);
            ss += __shfl_xor(ss, 2, 64);
            ss += __shfl_xor(ss, 4, 64);
            ss += __shfl_xor(ss, 8, 64);
            float rs = 1.0f / (sqrtf(ss) + EPSF);
            int own = (mt << 4) + (lgrp << 2) + j;
            __half* er = Hs + own * 132 + l15;
            #pragma unroll
            for (int nt = 0; nt < 8; nt++)
                er[nt << 4] = __float2half(acc[nt][j] * rs);
        }
    }
    __syncthreads();

    // ---- epilogue phase 2: coalesced writeback (8 uint2 / thread) -------
    {
        __half* ho = hout + ((size_t)b << 21);
        #pragma unroll
        for (int m = 0; m < 8; m++) {
            int c = (m << 8) + t;          // chunk 0..2047 (8 B each)
            int px = c >> 5, off = c & 31;
            uint2 v = *(const uint2*)(Hs + px * 132 + (off << 2));
            int gp2 = (ti0 + (px >> 3)) * WW + (tj0 + (px & 7));
            *(uint2*)(ho + (((size_t)gp2) << 7) + (off << 2)) = v;
        }
    }
}

// ---------------- mask head: h(fp16) @ w_mask, softmax(16), transpose ----
__global__ __launch_bounds__(256) void mask_kernel(
    const __half* __restrict__ h, const float* __restrict__ wm,
    float* __restrict__ out)
{
    __shared__ float wls[QQ * MM];      // 8 KB, [c][m] native layout
    __shared__ float part[64][4][20];   // [px][slot][16m + pad]
    const int t = threadIdx.x;
    for (int idx = t; idx < QQ * MM / 4; idx += 256)
        ((float4*)wls)[idx] = ((const float4*)wm)[idx];
    const int blk = blockIdx.x;         // 512
    const int b   = blk >> 8;
    const int n0  = (blk & 255) << 6;
    const int px  = t >> 2, s = t & 3;
    const __half* hr = h + (((size_t)(b << 14) + n0 + px) << 7);

    float hv[32];
    #pragma unroll
    for (int k = 0; k < 32; k++) hv[k] = __half2float(hr[s + (k << 2)]);
    __syncthreads();

    float4 a0 = {0,0,0,0}, a1 = a0, a2 = a0, a3 = a0;
    #pragma unroll
    for (int k = 0; k < 32; k++) {
        const float4* wrow = (const float4*)(wls + ((s + (k << 2)) << 4));
        float v = hv[k];
        float4 w0 = wrow[0], w1 = wrow[1], w2 = wrow[2], w3 = wrow[3];
        a0.x += v * w0.x; a0.y += v * w0.y; a0.z += v * w0.z; a0.w += v * w0.w;
        a1.x += v * w1.x; a1.y += v * w1.y; a1.z += v * w1.z; a1.w += v * w1.w;
        a2.x += v * w2.x; a2.y += v * w2.y; a2.z += v * w2.z; a2.w += v * w2.w;
        a3.x += v * w3.x; a3.y += v * w3.y; a3.z += v * w3.z; a3.w += v * w3.w;
    }
    *(float4*)&part[px][s][0]  = a0;
    *(float4*)&part[px][s][4]  = a1;
    *(float4*)&part[px][s][8]  = a2;
    *(float4*)&part[px][s][12] = a3;
    __syncthreads();

    float4 rr = {0,0,0,0};
    #pragma unroll
    for (int ss = 0; ss < 4; ss++) {
        float4 v = *(const float4*)&part[px][ss][s << 2];
        rr.x += v.x; rr.y += v.y; rr.z += v.z; rr.w += v.w;
    }
    float mx = fmaxf(fmaxf(rr.x, rr.y), fmaxf(rr.z, rr.w));
    mx = fmaxf(mx, __shfl_xor(mx, 1, 64));
    mx = fmaxf(mx, __shfl_xor(mx, 2, 64));
    float4 e = {expf(rr.x - mx), expf(rr.y - mx), expf(rr.z - mx), expf(rr.w - mx)};
    float ls = e.x + e.y + e.z + e.w;
    ls += __shfl_xor(ls, 1, 64);
    ls += __shfl_xor(ls, 2, 64);
    float inv = 1.0f / ls;
    float* ob = out + (((size_t)((b << 4) + (s << 2))) << 14) + n0 + px;
    ob[0]             = e.x * inv;
    ob[1 << 14]       = e.y * inv;
    ob[2 << 14]       = e.z * inv;
    ob[3 * (1 << 14)] = e.w * inv;
}

extern "C" void kernel_launch(void* const* d_in, const int* in_sizes, int n_in,
                              void* d_out, int out_size, void* d_ws, size_t ws_size,
                              hipStream_t stream)
{
    const float* x     = (const float*)d_in[0];
    // d_in[1] = edges (int32) -- unused: row/col are analytic
    const float* w1    = (const float*)d_in[2];
    const float* b1    = (const float*)d_in[3];
    const float* w2    = (const float*)d_in[4];
    const float* b2    = (const float*)d_in[5];
    const float* wk    = (const float*)d_in[6];
    const float* bk    = (const float*)d_in[7];
    const float* wq    = (const float*)d_in[8];
    const float* hinit = (const float*)d_in[9];
    const float* wm    = (const float*)d_in[10];
    float* out = (float*)d_out;

    char* ws = (char*)d_ws;
    size_t off = 0;
    auto alloc = [&](size_t bytes) -> void* {
        void* p = ws + off;
        off += (bytes + 255) & ~(size_t)255;
        return p;
    };
    float* feat1 = (float*)alloc((size_t)NBATCH * NPIX * DD * 4);
    float* feat2 = (float*)alloc((size_t)NBATCH * NPIX * DD * 4);
    float* ksb   = (float*)alloc((size_t)NBATCH * NPIX * DD * 4);
    float* qsb   = (float*)alloc((size_t)NBATCH * NPIX * DD * 4);
    float* knorm = (float*)alloc((size_t)NBATCH * NPIX * 4);
    float* qnorm = (float*)alloc((size_t)NBATCH * NPIX * 4);
    float* wT    = (float*)alloc((size_t)NBATCH * NPIX * 32 * 4);
    __half* Wg   = (__half*)alloc((size_t)512 * 9216 * 2);
    __half* h16A = (__half*)alloc((size_t)NBATCH * NPIX * QQ * 2);
    __half* h16B = (__half*)alloc((size_t)NBATCH * NPIX * QQ * 2);

    conv1_kernel<<<512, 256, 0, stream>>>(x, w1, b1, feat1);
    conv2_kernel<<<512, 256, 0, stream>>>(feat1, w2, b2, feat2);
    kq_kernel<<<4096, 256, 0, stream>>>(feat2, wk, bk, wq, ksb, qsb, knorm, qnorm);
    edge_kernel<<<512, 256, 0, stream>>>(ksb, qsb, knorm, qnorm, wT);
    wpack_kernel<<<512, 256, 0, stream>>>(wT, Wg);

    // iteration 0 reads fp32 hinit directly; 31 more fp16-to-fp16
    prop_mfma_kernel<true><<<512, 256, 0, stream>>>((const void*)hinit, h16A, Wg);

    const __half* src = h16A;
    __half* dst = h16B;
    for (int it = 1; it < 32; it++) {
        prop_mfma_kernel<false><<<512, 256, 0, stream>>>((const void*)src, dst, Wg);
        src = dst;
        dst = (dst == h16A) ? h16B : h16A;
    }
    mask_kernel<<<512, 256, 0, stream>>>(src, wm, out);
}

// Round 18
// 328.552 us; speedup vs baseline: 1.0511x; 1.0511x over previous
//
#include <hip/hip_runtime.h>
#include <hip/hip_fp16.h>
#include <math.h>

#define HH 128
#define WW 128
#define NPIX 16384
#define CIN 3
#define DD 32
#define QQ 128
#define MM 16
#define NBATCH 2
#define EPSF 1e-8f

typedef _Float16 half4_t __attribute__((ext_vector_type(4)));
typedef float f32x4_t __attribute__((ext_vector_type(4)));

// ---------------- conv1: 3x3, 3->32, relu, zero-pad SAME ----------------
__global__ __launch_bounds__(256) void conv1_kernel(
    const float* __restrict__ x, const float* __restrict__ w1,
    const float* __restrict__ b1, float* __restrict__ out)
{
    __shared__ float wlds[9 * CIN * DD];
    int t = threadIdx.x;
    for (int idx = t; idx < 9 * CIN * DD / 4; idx += 256)
        ((float4*)wlds)[idx] = ((const float4*)w1)[idx];
    __syncthreads();

    int ocq = t & 3;
    int pl  = t >> 2;
    int blk = blockIdx.x;                   // 512
    int b   = blk >> 8;
    int pix = (blk & 255) * 64 + pl;
    int i = pix >> 7, j = pix & 127;
    int ocb = ocq << 3;

    float4 acc0 = *(const float4*)(b1 + ocb);
    float4 acc1 = *(const float4*)(b1 + ocb + 4);
    #pragma unroll
    for (int dy = 0; dy < 3; dy++) {
        int ii = i + dy - 1;
        if (ii < 0 || ii >= HH) continue;
        #pragma unroll
        for (int dx = 0; dx < 3; dx++) {
            int jj = j + dx - 1;
            if (jj < 0 || jj >= WW) continue;
            const float* fr = x + ((size_t)((b << 14) + ii * WW + jj)) * CIN;
            float in0 = fr[0], in1 = fr[1], in2 = fr[2];
            const float* wp = wlds + (size_t)((dy * 3 + dx) * CIN) * DD + ocb;
            #pragma unroll
            for (int ic = 0; ic < 3; ic++) {
                float inv = (ic == 0) ? in0 : (ic == 1) ? in1 : in2;
                float4 w0 = *(const float4*)(wp + ic * DD);
                float4 w1v = *(const float4*)(wp + ic * DD + 4);
                acc0.x += inv * w0.x;  acc0.y += inv * w0.y;
                acc0.z += inv * w0.z;  acc0.w += inv * w0.w;
                acc1.x += inv * w1v.x; acc1.y += inv * w1v.y;
                acc1.z += inv * w1v.z; acc1.w += inv * w1v.w;
            }
        }
    }
    float* op = out + (((size_t)(b << 14) + pix) << 5) + ocb;
    float4 r0 = {fmaxf(acc0.x, 0.f), fmaxf(acc0.y, 0.f), fmaxf(acc0.z, 0.f), fmaxf(acc0.w, 0.f)};
    float4 r1 = {fmaxf(acc1.x, 0.f), fmaxf(acc1.y, 0.f), fmaxf(acc1.z, 0.f), fmaxf(acc1.w, 0.f)};
    *(float4*)op = r0;
    *(float4*)(op + 4) = r1;
}

// ---------------- conv2: 3x3, 32->32, relu (proven R7 version) -----------
__global__ __launch_bounds__(256) void conv2_kernel(
    const float* __restrict__ fin, const float* __restrict__ w2,
    const float* __restrict__ b2, float* __restrict__ out)
{
    __shared__ float wlds[9 * DD * DD];    // 36.9 KB
    int t = threadIdx.x;
    for (int idx = t; idx < 9 * DD * DD / 4; idx += 256)
        ((float4*)wlds)[idx] = ((const float4*)w2)[idx];
    __syncthreads();

    int ocq = t & 3;
    int pl  = t >> 2;
    int blk = blockIdx.x;                   // 512
    int b   = blk >> 8;
    int pix = (blk & 255) * 64 + pl;
    int i = pix >> 7, j = pix & 127;
    int ocb = ocq << 3;

    float4 acc0 = *(const float4*)(b2 + ocb);
    float4 acc1 = *(const float4*)(b2 + ocb + 4);
    #pragma unroll
    for (int dy = 0; dy < 3; dy++) {
        int ii = i + dy - 1;
        if (ii < 0 || ii >= HH) continue;
        #pragma unroll
        for (int dx = 0; dx < 3; dx++) {
            int jj = j + dx - 1;
            if (jj < 0 || jj >= WW) continue;
            const float* fr = fin + (((size_t)(b << 14) + ii * WW + jj)) * DD;
            float iv[DD];
            #pragma unroll
            for (int c = 0; c < DD / 4; c++)
                ((float4*)iv)[c] = *(const float4*)(fr + c * 4);
            const float* wp = wlds + (size_t)((dy * 3 + dx) * DD) * DD + ocb;
            #pragma unroll
            for (int ic = 0; ic < DD; ic++) {
                float inv = iv[ic];
                float4 w0 = *(const float4*)(wp + ic * DD);
                float4 w1v = *(const float4*)(wp + ic * DD + 4);
                acc0.x += inv * w0.x;  acc0.y += inv * w0.y;
                acc0.z += inv * w0.z;  acc0.w += inv * w0.w;
                acc1.x += inv * w1v.x; acc1.y += inv * w1v.y;
                acc1.z += inv * w1v.z; acc1.w += inv * w1v.w;
            }
        }
    }
    float* op = out + (((size_t)(b << 14) + pix) << 5) + ocb;
    float4 r0 = {fmaxf(acc0.x, 0.f), fmaxf(acc0.y, 0.f), fmaxf(acc0.z, 0.f), fmaxf(acc0.w, 0.f)};
    float4 r1 = {fmaxf(acc1.x, 0.f), fmaxf(acc1.y, 0.f), fmaxf(acc1.z, 0.f), fmaxf(acc1.w, 0.f)};
    *(float4*)op = r0;
    *(float4*)(op + 4) = r1;
}

// ---------------- k/q 1x1 projections + row norms ----------------
__global__ __launch_bounds__(256) void kq_kernel(
    const float* __restrict__ fin, const float* __restrict__ wk,
    const float* __restrict__ bk, const float* __restrict__ wq,
    float* __restrict__ ksb, float* __restrict__ qsb,
    float* __restrict__ knorm, float* __restrict__ qnorm)
{
    int g  = blockIdx.x * 256 + threadIdx.x;  // B*N*32
    int oc = g & 31;
    int bp = g >> 5;
    const float* fr = fin + (size_t)bp * DD;
    float ak = bk[oc], aq = 0.0f;
    #pragma unroll
    for (int ic = 0; ic < DD; ic += 4) {
        float4 fv = *(const float4*)(fr + ic);
        ak += fv.x * wk[(ic + 0) * DD + oc];
        ak += fv.y * wk[(ic + 1) * DD + oc];
        ak += fv.z * wk[(ic + 2) * DD + oc];
        ak += fv.w * wk[(ic + 3) * DD + oc];
        aq += fv.x * wq[(ic + 0) * DD + oc];
        aq += fv.y * wq[(ic + 1) * DD + oc];
        aq += fv.z * wq[(ic + 2) * DD + oc];
        aq += fv.w * wq[(ic + 3) * DD + oc];
    }
    ksb[g] = ak;
    qsb[g] = aq;
    float ssk = ak * ak, ssq = aq * aq;
    #pragma unroll
    for (int m = 1; m < 32; m <<= 1) {
        ssk += __shfl_xor(ssk, m, 64);
        ssq += __shfl_xor(ssq, m, 64);
    }
    if (oc == 0) {
        knorm[bp] = sqrtf(ssk);
        qnorm[bp] = sqrtf(ssq);
    }
}

// ---------------- edge scores FUSED with W-pack --------------------------
// Computes exp(cosine) per (own px, neighbor) and writes the dense
// zero-padded fp16 W[64 own][144 halo] for this tile DIRECTLY to Wg
// (wT buffer + wpack dispatch eliminated; weights bit-identical).
// Block->tile decode matches prop_mfma_kernel's XCD-swizzled decode
// (bijective relabeling of the 512 (b,tile) pairs).
__global__ __launch_bounds__(256) void edge_kernel(
    const float* __restrict__ ksb, const float* __restrict__ qsb,
    const float* __restrict__ knorm, const float* __restrict__ qnorm,
    __half* __restrict__ Wg)
{
    __shared__ float kt[144][36];   // +4 pad: breaks 32-stride bank aliasing
    __shared__ float qt[64][36];
    __shared__ float kn[144];
    __shared__ float qn[64];
    __shared__ __half Wl[64 * 144]; // 18.4 KB packed fp16 weights
    const int t   = threadIdx.x;
    const int blk = blockIdx.x;     // 512
    const int x   = blk & 7;        // prop-matching XCD-swizzled decode
    const int r   = blk >> 3;
    const int g_tr = (x << 2) + (r >> 4);
    const int b   = g_tr >> 4;
    const int ti0 = (g_tr & 15) << 3;
    const int tj0 = (r & 15) << 3;
    const float* kb = ksb + ((size_t)b << 19);
    const float* qb = qsb + ((size_t)b << 19);

    for (int idx = t; idx < 1152; idx += 256)
        ((uint4*)Wl)[idx] = (uint4){0u, 0u, 0u, 0u};

    for (int idx = t; idx < 144 * 8; idx += 256) {
        int row = idx >> 3, quad = idx & 7;
        int ar = row / 12, ac = row - ar * 12;
        int gi = min(max(ti0 + ar - 2, 0), HH - 1);
        int gj = min(max(tj0 + ac - 2, 0), WW - 1);
        *(float4*)&kt[row][quad << 2] =
            *(const float4*)(kb + ((size_t)(gi * WW + gj) << 5) + (quad << 2));
    }
    for (int idx = t; idx < 64 * 8; idx += 256) {
        int row = idx >> 3, quad = idx & 7;
        int gp = (ti0 + (row >> 3)) * WW + tj0 + (row & 7);
        *(float4*)&qt[row][quad << 2] =
            *(const float4*)(qb + ((size_t)gp << 5) + (quad << 2));
    }
    if (t < 144) {
        int ar = t / 12, ac = t - ar * 12;
        int gi = min(max(ti0 + ar - 2, 0), HH - 1);
        int gj = min(max(tj0 + ac - 2, 0), WW - 1);
        kn[t] = knorm[(b << 14) + gi * WW + gj];
    } else if (t < 208) {
        int r2 = t - 144;
        int gp = (ti0 + (r2 >> 3)) * WW + tj0 + (r2 & 7);
        qn[r2] = qnorm[(b << 14) + gp];
    }
    __syncthreads();

    const int nl = t >> 2, s = t & 3;
    const int p = nl >> 3, q = nl & 7;
    float4 qv[8];
    #pragma unroll
    for (int c = 0; c < 8; c++) qv[c] = *(const float4*)&qt[nl][c << 2];
    const float qnv = qn[nl];
    for (int o = s; o < 25; o += 4) {
        int di = o / 5, dj = o - di * 5;      // 0..4
        int krow = (p + di) * 12 + (q + dj);  // halo coords (all 25 distinct)
        const float* kr = &kt[krow][0];
        float dot = 0.0f;
        #pragma unroll
        for (int c = 0; c < 8; c++) {
            float4 kv = *(const float4*)(kr + (c << 2));
            dot += qv[c].x * kv.x + qv[c].y * kv.y + qv[c].z * kv.z + qv[c].w * kv.w;
        }
        float den = fmaxf(qnv * kn[krow], EPSF);
        Wl[nl * 144 + krow] = __float2half(expf(dot / den));
    }
    __syncthreads();

    uint4* dst = (uint4*)(Wg + (size_t)blk * 9216);
    for (int idx = t; idx < 1152; idx += 256)
        dst[idx] = ((uint4*)Wl)[idx];
}

// ---------------- propagation iteration: MFMA 16x16x16 GEMM --------------
// (R16-proven, 333.6 us: crossbar tr-read, K=144 = 9 x mfma_16x16x16f16,
// A from L2-resident Wg, one barrier, rule-18 fences, direct scattered
// epilogue stores -- R17's LDS-transpose epilogue regressed and was
// reverted.)
template<bool FIRST>
__global__ __launch_bounds__(256) void prop_mfma_kernel(
    const void* __restrict__ hin_v, __half* __restrict__ hout,
    const __half* __restrict__ Wg)
{
    __shared__ __half Hs[8 * 2320];        // 37,120 B: [nt][144][16] + 16 pad
    const int t = threadIdx.x;
    const int x = blockIdx.x & 7;          // XCD slab
    const int r = blockIdx.x >> 3;
    const int g_tr = (x << 2) + (r >> 4);
    const int b   = g_tr >> 4;
    const int ti0 = (g_tr & 15) << 3;
    const int tj0 = (r & 15) << 3;

    const int s = t & 15, g = t >> 4;
    // stage H: 9 halo px/thread, 8 ch (ch = s*8..s*8+7 -> nt=s>>1, hi=s&1)
    {
        const int nt_s = s >> 1, hi = s & 1;
        uint4* hd = (uint4*)Hs;
        #pragma unroll
        for (int n = 0; n < 9; n++) {
            int a = (n << 4) + g;
            int ar = a / 12, ac = a - ar * 12;
            int gi = min(max(ti0 + ar - 2, 0), HH - 1);
            int gj = min(max(tj0 + ac - 2, 0), WW - 1);
            size_t src = (((size_t)(b << 14) + gi * WW + gj) << 7) + (s << 3);
            uint4 v;
            if constexpr (FIRST) {
                const float* hb = (const float*)hin_v;
                float4 f0 = *(const float4*)(hb + src);
                float4 f1 = *(const float4*)(hb + src + 4);
                __half2 p0 = __floats2half2_rn(f0.x, f0.y);
                __half2 p1 = __floats2half2_rn(f0.z, f0.w);
                __half2 p2 = __floats2half2_rn(f1.x, f1.y);
                __half2 p3 = __floats2half2_rn(f1.z, f1.w);
                v.x = *(unsigned*)&p0; v.y = *(unsigned*)&p1;
                v.z = *(unsigned*)&p2; v.w = *(unsigned*)&p3;
            } else {
                const __half* hb = (const __half*)hin_v;
                v = *(const uint4*)(hb + src);
            }
            hd[nt_s * 290 + (a << 1) + hi] = v;   // halves: nt*2320 + a*16 + hi*8
        }
    }

    const int mt = t >> 6, lane = t & 63;
    const int l15 = lane & 15, lgrp = lane >> 4;

    // A-fragments from L2-resident Wg: lane reads W[mt*16+l15][kk*16+lgrp*4 ..+3]
    const __half* wrow_g = Wg + (size_t)blockIdx.x * 9216
                              + ((mt << 4) + l15) * 144 + (lgrp << 2);
    half4_t Af[9];
    #pragma unroll
    for (int kk = 0; kk < 9; kk++)
        Af[kk] = *(const half4_t*)(wrow_g + (kk << 4));

    __syncthreads();

    f32x4_t acc[8];
    #pragma unroll
    for (int nt = 0; nt < 8; nt++) acc[nt] = (f32x4_t){0.f, 0.f, 0.f, 0.f};

    // crossbar addressing: lane covers its own 8 B of the group's 128-B
    // 4x16 window; window = rows lgrp*4..lgrp*4+3 of the kk K-subtile
    const unsigned hsb = (unsigned)(size_t)&Hs[0]
                       + ((unsigned)l15 << 3) + ((unsigned)lgrp << 7);
    #pragma unroll
    for (int nt = 0; nt < 8; nt++) {
        unsigned base = hsb + (unsigned)nt * 4640u;
        unsigned long long r0, r1, r2, r3, r4, r5, r6, r7, r8;
        asm volatile("ds_read_b64_tr_b16 %0, %1"              : "=v"(r0) : "v"(base));
        asm volatile("ds_read_b64_tr_b16 %0, %1 offset:512"   : "=v"(r1) : "v"(base));
        asm volatile("ds_read_b64_tr_b16 %0, %1 offset:1024"  : "=v"(r2) : "v"(base));
        asm volatile("ds_read_b64_tr_b16 %0, %1 offset:1536"  : "=v"(r3) : "v"(base));
        asm volatile("ds_read_b64_tr_b16 %0, %1 offset:2048"  : "=v"(r4) : "v"(base));
        asm volatile("ds_read_b64_tr_b16 %0, %1 offset:2560"  : "=v"(r5) : "v"(base));
        asm volatile("ds_read_b64_tr_b16 %0, %1 offset:3072"  : "=v"(r6) : "v"(base));
        asm volatile("ds_read_b64_tr_b16 %0, %1 offset:3584"  : "=v"(r7) : "v"(base));
        asm volatile("ds_read_b64_tr_b16 %0, %1 offset:4096"  : "=v"(r8) : "v"(base));
        asm volatile("s_waitcnt lgkmcnt(0)" ::: "memory");
        __builtin_amdgcn_sched_barrier(0);
        union { unsigned long long u; half4_t h; } b0, b1, b2, b3, b4, b5, b6, b7, b8;
        b0.u = r0; b1.u = r1; b2.u = r2; b3.u = r3; b4.u = r4;
        b5.u = r5; b6.u = r6; b7.u = r7; b8.u = r8;
        acc[nt] = __builtin_amdgcn_mfma_f32_16x16x16f16(Af[0], b0.h, acc[nt], 0, 0, 0);
        acc[nt] = __builtin_amdgcn_mfma_f32_16x16x16f16(Af[1], b1.h, acc[nt], 0, 0, 0);
        acc[nt] = __builtin_amdgcn_mfma_f32_16x16x16f16(Af[2], b2.h, acc[nt], 0, 0, 0);
        acc[nt] = __builtin_amdgcn_mfma_f32_16x16x16f16(Af[3], b3.h, acc[nt], 0, 0, 0);
        acc[nt] = __builtin_amdgcn_mfma_f32_16x16x16f16(Af[4], b4.h, acc[nt], 0, 0, 0);
        acc[nt] = __builtin_amdgcn_mfma_f32_16x16x16f16(Af[5], b5.h, acc[nt], 0, 0, 0);
        acc[nt] = __builtin_amdgcn_mfma_f32_16x16x16f16(Af[6], b6.h, acc[nt], 0, 0, 0);
        acc[nt] = __builtin_amdgcn_mfma_f32_16x16x16f16(Af[7], b7.h, acc[nt], 0, 0, 0);
        acc[nt] = __builtin_amdgcn_mfma_f32_16x16x16f16(Af[8], b8.h, acc[nt], 0, 0, 0);
    }

    // epilogue: own = mt*16 + lgrp*4 + j, ch = nt*16 + l15; norm over ch
    __half* ho = hout + ((size_t)b << 21);
    #pragma unroll
    for (int j = 0; j < 4; j++) {
        float ss = 0.0f;
        #pragma unroll
        for (int nt = 0; nt < 8; nt++) { float v = acc[nt][j]; ss += v * v; }
        ss += __shfl_xor(ss, 1, 64);
        ss += __shfl_xor(ss, 2, 64);
        ss += __shfl_xor(ss, 4, 64);
        ss += __shfl_xor(ss, 8, 64);
        float rs = 1.0f / (sqrtf(ss) + EPSF);
        int own = (mt << 4) + (lgrp << 2) + j;
        int gp = (ti0 + (own >> 3)) * WW + (tj0 + (own & 7));
        __half* orow = ho + (((size_t)gp) << 7) + l15;
        #pragma unroll
        for (int nt = 0; nt < 8; nt++)
            orow[nt << 4] = __float2half(acc[nt][j] * rs);
    }
}

// ---------------- mask head: h(fp16) @ w_mask, softmax(16), transpose ----
__global__ __launch_bounds__(256) void mask_kernel(
    const __half* __restrict__ h, const float* __restrict__ wm,
    float* __restrict__ out)
{
    __shared__ float wls[QQ * MM];      // 8 KB, [c][m] native layout
    __shared__ float part[64][4][20];   // [px][slot][16m + pad]
    const int t = threadIdx.x;
    for (int idx = t; idx < QQ * MM / 4; idx += 256)
        ((float4*)wls)[idx] = ((const float4*)wm)[idx];
    const int blk = blockIdx.x;         // 512
    const int b   = blk >> 8;
    const int n0  = (blk & 255) << 6;
    const int px  = t >> 2, s = t & 3;
    const __half* hr = h + (((size_t)(b << 14) + n0 + px) << 7);

    float hv[32];
    #pragma unroll
    for (int k = 0; k < 32; k++) hv[k] = __half2float(hr[s + (k << 2)]);
    __syncthreads();

    float4 a0 = {0,0,0,0}, a1 = a0, a2 = a0, a3 = a0;
    #pragma unroll
    for (int k = 0; k < 32; k++) {
        const float4* wrow = (const float4*)(wls + ((s + (k << 2)) << 4));
        float v = hv[k];
        float4 w0 = wrow[0], w1 = wrow[1], w2 = wrow[2], w3 = wrow[3];
        a0.x += v * w0.x; a0.y += v * w0.y; a0.z += v * w0.z; a0.w += v * w0.w;
        a1.x += v * w1.x; a1.y += v * w1.y; a1.z += v * w1.z; a1.w += v * w1.w;
        a2.x += v * w2.x; a2.y += v * w2.y; a2.z += v * w2.z; a2.w += v * w2.w;
        a3.x += v * w3.x; a3.y += v * w3.y; a3.z += v * w3.z; a3.w += v * w3.w;
    }
    *(float4*)&part[px][s][0]  = a0;
    *(float4*)&part[px][s][4]  = a1;
    *(float4*)&part[px][s][8]  = a2;
    *(float4*)&part[px][s][12] = a3;
    __syncthreads();

    float4 rr = {0,0,0,0};
    #pragma unroll
    for (int ss = 0; ss < 4; ss++) {
        float4 v = *(const float4*)&part[px][ss][s << 2];
        rr.x += v.x; rr.y += v.y; rr.z += v.z; rr.w += v.w;
    }
    float mx = fmaxf(fmaxf(rr.x, rr.y), fmaxf(rr.z, rr.w));
    mx = fmaxf(mx, __shfl_xor(mx, 1, 64));
    mx = fmaxf(mx, __shfl_xor(mx, 2, 64));
    float4 e = {expf(rr.x - mx), expf(rr.y - mx), expf(rr.z - mx), expf(rr.w - mx)};
    float ls = e.x + e.y + e.z + e.w;
    ls += __shfl_xor(ls, 1, 64);
    ls += __shfl_xor(ls, 2, 64);
    float inv = 1.0f / ls;
    float* ob = out + (((size_t)((b << 4) + (s << 2))) << 14) + n0 + px;
    ob[0]             = e.x * inv;
    ob[1 << 14]       = e.y * inv;
    ob[2 << 14]       = e.z * inv;
    ob[3 * (1 << 14)] = e.w * inv;
}

extern "C" void kernel_launch(void* const* d_in, const int* in_sizes, int n_in,
                              void* d_out, int out_size, void* d_ws, size_t ws_size,
                              hipStream_t stream)
{
    const float* x     = (const float*)d_in[0];
    // d_in[1] = edges (int32) -- unused: row/col are analytic
    const float* w1    = (const float*)d_in[2];
    const float* b1    = (const float*)d_in[3];
    const float* w2    = (const float*)d_in[4];
    const float* b2    = (const float*)d_in[5];
    const float* wk    = (const float*)d_in[6];
    const float* bk    = (const float*)d_in[7];
    const float* wq    = (const float*)d_in[8];
    const float* hinit = (const float*)d_in[9];
    const float* wm    = (const float*)d_in[10];
    float* out = (float*)d_out;

    char* ws = (char*)d_ws;
    size_t off = 0;
    auto alloc = [&](size_t bytes) -> void* {
        void* p = ws + off;
        off += (bytes + 255) & ~(size_t)255;
        return p;
    };
    float* feat1 = (float*)alloc((size_t)NBATCH * NPIX * DD * 4);
    float* feat2 = (float*)alloc((size_t)NBATCH * NPIX * DD * 4);
    float* ksb   = (float*)alloc((size_t)NBATCH * NPIX * DD * 4);
    float* qsb   = (float*)alloc((size_t)NBATCH * NPIX * DD * 4);
    float* knorm = (float*)alloc((size_t)NBATCH * NPIX * 4);
    float* qnorm = (float*)alloc((size_t)NBATCH * NPIX * 4);
    __half* Wg   = (__half*)alloc((size_t)512 * 9216 * 2);
    __half* h16A = (__half*)alloc((size_t)NBATCH * NPIX * QQ * 2);
    __half* h16B = (__half*)alloc((size_t)NBATCH * NPIX * QQ * 2);

    conv1_kernel<<<512, 256, 0, stream>>>(x, w1, b1, feat1);
    conv2_kernel<<<512, 256, 0, stream>>>(feat1, w2, b2, feat2);
    kq_kernel<<<4096, 256, 0, stream>>>(feat2, wk, bk, wq, ksb, qsb, knorm, qnorm);
    edge_kernel<<<512, 256, 0, stream>>>(ksb, qsb, knorm, qnorm, Wg);

    // iteration 0 reads fp32 hinit directly; 31 more fp16-to-fp16
    prop_mfma_kernel<true><<<512, 256, 0, stream>>>((const void*)hinit, h16A, Wg);

    const __half* src = h16A;
    __half* dst = h16B;
    for (int it = 1; it < 32; it++) {
        prop_mfma_kernel<false><<<512, 256, 0, stream>>>((const void*)src, dst, Wg);
        src = dst;
        dst = (dst == h16A) ? h16B : h16A;
    }
    mask_kernel<<<512, 256, 0, stream>>>(src, wm, out);
}